// Round 4
// baseline (574.709 us; speedup 1.0000x reference)
//
#include <hip/hip_runtime.h>

typedef __attribute__((ext_vector_type(8))) __bf16 bf16x8;
typedef __attribute__((ext_vector_type(4))) float f32x4;
typedef __attribute__((ext_vector_type(8))) unsigned short u16x8;
typedef __attribute__((ext_vector_type(4))) unsigned short u16x4;

#define B_SZ 512
#define N_SZ 256
#define H_SZ 128

__device__ __forceinline__ float bf2f(unsigned short u) {
    unsigned int x = ((unsigned int)u) << 16;
    return __builtin_bit_cast(float, x);
}
__device__ __forceinline__ unsigned short f2bf(float f) {
    unsigned int x = __builtin_bit_cast(unsigned int, f);
    x += 0x7FFFu + ((x >> 16) & 1u);
    return (unsigned short)(x >> 16);
}

// ---------------------------------------------------------------------------
// K0: detect idx element width. int64 (values < 50000) -> all odd int32 words
// zero. int32 real data -> some odd word nonzero. flag=1 -> int32.
// ---------------------------------------------------------------------------
__global__ void detect_kernel(const int* __restrict__ idx, int* __restrict__ flag) {
    __shared__ int red;
    int tid = threadIdx.x;
    if (tid == 0) red = 0;
    __syncthreads();
    int any = 0;
    for (int p = tid; p < 65536; p += 256) any |= (idx[2 * p + 1] != 0);
    if (any) atomicOr(&red, 1);
    __syncthreads();
    if (tid == 0) flag[0] = red;
}

// ---------------------------------------------------------------------------
// K1: A (f32 [512,256,512]) -> A2 = A[:,:,:256] + A[:,:,256:] (bf16)
//     plus d[row] = 1/sqrt(rowsum(A2) + 1)  (fp32)
// one wave per row, lane covers j = lane*4 .. lane*4+3 from both halves
// ---------------------------------------------------------------------------
__global__ __launch_bounds__(256) void rowsum_kernel(const float* __restrict__ A,
                                                     unsigned short* __restrict__ A2,
                                                     float* __restrict__ d) {
    int row = blockIdx.x * 4 + (threadIdx.x >> 6);
    int lane = threadIdx.x & 63;
    const float* p = A + (size_t)row * 512 + lane * 4;
    f32x4 vin = *(const f32x4*)p;
    f32x4 vout = *(const f32x4*)(p + 256);
    f32x4 a2 = vin + vout;
    float s = a2[0] + a2[1] + a2[2] + a2[3];
    u16x4 pk;
#pragma unroll
    for (int e = 0; e < 4; e++) pk[e] = f2bf(a2[e]);
    *(u16x4*)(A2 + (size_t)row * 256 + lane * 4) = pk;
#pragma unroll
    for (int m = 32; m >= 1; m >>= 1) s += __shfl_xor(s, m, 64);
    if (lane == 0) d[row] = 1.0f / sqrtf(s + 1.0f);  // rowsum >= 1, never inf
}

// ---------------------------------------------------------------------------
// K2 (in place): A2[b,i,j] <- 0.8*norm + (i==j ? 0.1*(1-norm) : 0)
//     norm = (A2 + (i==j)) * d_i * d_j
// each element read+written by the same thread -> race-free in place
// ---------------------------------------------------------------------------
__global__ __launch_bounds__(256) void mix_kernel(unsigned short* __restrict__ A2,
                                                  const float* __restrict__ d) {
    int tid = threadIdx.x;
    int row = blockIdx.x * 8 + (tid >> 5);  // global row = b*256 + i
    int b = row >> 8;
    int i = row & 255;
    int jb = (tid & 31) * 8;
    unsigned short* Ar = A2 + (size_t)row * 256 + jb;
    u16x8 v = *(const u16x8*)Ar;
    float di = d[row];
    const float* dj = d + b * 256 + jb;
    u16x8 res;
#pragma unroll
    for (int e = 0; e < 8; e++) {
        float a = bf2f(v[e]);
        bool diag = (i == jb + e);
        if (diag) a += 1.0f;
        float na = a * di * dj[e];
        float val = 0.8f * na;
        if (diag) val += 0.1f * (1.0f - na);
        res[e] = f2bf(val);
    }
    *(u16x8*)Ar = res;
}

// ---------------------------------------------------------------------------
// K3: gather + transpose: outT[b, h, j] = bf16(emb[idx[b,j], h]), emb f32
// block = (j-block of 64) x (all 128 h); LDS transpose for coalesced writes
// ---------------------------------------------------------------------------
__global__ __launch_bounds__(256) void gather_kernel(const int* __restrict__ idx,
                                                     const float* __restrict__ emb,
                                                     const int* __restrict__ flag,
                                                     unsigned short* __restrict__ outT) {
    __shared__ unsigned short tileT[128 * 72];  // [h][jj], stride 72
    int b = blockIdx.y;
    int j0 = blockIdx.x * 64;
    int tid = threadIdx.x;
    int jj = tid & 63;
    int hw = tid >> 6;
    int pos = b * 256 + j0 + jj;
    int node = (flag[0] != 0) ? idx[pos] : idx[2 * pos];  // int64: low word
    const float* erow = emb + (size_t)node * 128;
#pragma unroll
    for (int p = 0; p < 4; p++) {
        int h0 = hw * 8 + p * 32;
        f32x4 v0 = *(const f32x4*)(erow + h0);
        f32x4 v1 = *(const f32x4*)(erow + h0 + 4);
#pragma unroll
        for (int e = 0; e < 4; e++) tileT[(h0 + e) * 72 + jj] = f2bf(v0[e]);
#pragma unroll
        for (int e = 0; e < 4; e++) tileT[(h0 + 4 + e) * 72 + jj] = f2bf(v1[e]);
    }
    __syncthreads();
#pragma unroll
    for (int p = 0; p < 4; p++) {
        int h = (tid >> 3) + p * 32;
        int jc = (tid & 7) * 8;
        u16x8 v = *(const u16x8*)(&tileT[h * 72 + jc]);
        *(u16x8*)(outT + ((size_t)b * 128 + h) * 256 + j0 + jc) = v;
    }
}

// ---------------------------------------------------------------------------
// K4/K5: per-batch GEMM  C[i,h] = sum_j Amix[b,i,j] * HT[b,h,j]
// A-op = Amix (m=i,k=j), B-op = HT rows (n=h,k=j) -> both contiguous-k in LDS.
// block: 64 m-rows x all 128 h; 4 waves, each 64x32; K-loop BK=32, 8 mfma/step.
// mode 0: write bf16 transposed outT[b,h,i] (intermediate, packed 8B stores)
// mode 1: write FP32 normal   outF[b,i,h]  (final output buffer is float*)
// ---------------------------------------------------------------------------
__global__ __launch_bounds__(256) void gemm_kernel(const unsigned short* __restrict__ Amix,
                                                   const unsigned short* __restrict__ HT,
                                                   unsigned short* __restrict__ outT,
                                                   float* __restrict__ outF,
                                                   int mode) {
    __shared__ unsigned short As[64 * 40];   // [m][k] stride 40
    __shared__ unsigned short Bs[128 * 40];  // [h][k] stride 40
    int b = blockIdx.y;
    int m0 = blockIdx.x * 64;
    int tid = threadIdx.x;
    int w = tid >> 6;
    int lane = tid & 63;
    int q = lane >> 4;
    int ln = lane & 15;
    int n0 = w * 32;

    f32x4 acc[4][2];
#pragma unroll
    for (int mt = 0; mt < 4; mt++)
#pragma unroll
        for (int nt = 0; nt < 2; nt++) acc[mt][nt] = f32x4{0.f, 0.f, 0.f, 0.f};

    const unsigned short* Ab = Amix + ((size_t)b * 256 + m0) * 256;
    const unsigned short* Hb = HT + (size_t)b * 128 * 256;

    int ar = tid >> 2, ac = (tid & 3) * 8;
    int br = tid >> 1, bc = (tid & 1) * 16;

    for (int k0 = 0; k0 < 256; k0 += 32) {
        u16x8 av = *(const u16x8*)(Ab + ar * 256 + k0 + ac);
        u16x8 bv0 = *(const u16x8*)(Hb + br * 256 + k0 + bc);
        u16x8 bv1 = *(const u16x8*)(Hb + br * 256 + k0 + bc + 8);
        *(u16x8*)(&As[ar * 40 + ac]) = av;
        *(u16x8*)(&Bs[br * 40 + bc]) = bv0;
        *(u16x8*)(&Bs[br * 40 + bc + 8]) = bv1;
        __syncthreads();
        bf16x8 afrag[4], bfrag[2];
#pragma unroll
        for (int mt = 0; mt < 4; mt++)
            afrag[mt] = *(const bf16x8*)(&As[(mt * 16 + ln) * 40 + q * 8]);
#pragma unroll
        for (int nt = 0; nt < 2; nt++)
            bfrag[nt] = *(const bf16x8*)(&Bs[(n0 + nt * 16 + ln) * 40 + q * 8]);
#pragma unroll
        for (int mt = 0; mt < 4; mt++)
#pragma unroll
            for (int nt = 0; nt < 2; nt++)
                acc[mt][nt] = __builtin_amdgcn_mfma_f32_16x16x32_bf16(afrag[mt], bfrag[nt],
                                                                      acc[mt][nt], 0, 0, 0);
        __syncthreads();
    }

    if (mode == 0) {
        // C/D layout: col(h)=ln, row(i)=q*4+reg -> regs are i-consecutive
#pragma unroll
        for (int mt = 0; mt < 4; mt++)
#pragma unroll
            for (int nt = 0; nt < 2; nt++) {
                int h = n0 + nt * 16 + ln;
                int i0 = m0 + mt * 16 + q * 4;
                u16x4 pk;
#pragma unroll
                for (int r = 0; r < 4; r++) pk[r] = f2bf(acc[mt][nt][r]);
                *(u16x4*)(outT + ((size_t)b * 128 + h) * 256 + i0) = pk;
            }
    } else {
#pragma unroll
        for (int mt = 0; mt < 4; mt++)
#pragma unroll
            for (int nt = 0; nt < 2; nt++) {
                int h = n0 + nt * 16 + ln;
                int i0 = m0 + mt * 16 + q * 4;
#pragma unroll
                for (int r = 0; r < 4; r++)
                    outF[((size_t)b * 256 + i0 + r) * 128 + h] = acc[mt][nt][r];
            }
    }
}

extern "C" void kernel_launch(void* const* d_in, const int* in_sizes, int n_in,
                              void* d_out, int out_size, void* d_ws, size_t ws_size,
                              hipStream_t stream) {
    const int* idx = (const int*)d_in[0];        // [512,256] int32 or int64
    const float* A = (const float*)d_in[1];      // [512,256,512] f32
    const float* emb = (const float*)d_in[2];    // [50000,128] f32
    float* out = (float*)d_out;                  // [512,256,128] FP32 (ref output dtype)

    char* ws = (char*)d_ws;
    int* flag = (int*)ws;                                      // 4 B
    float* d = (float*)(ws + 4096);                            // 512 KB
    unsigned short* A2 = (unsigned short*)(ws + 528384);       // 64 MB (A2 -> Amix in place)
    unsigned short* h0T = (unsigned short*)(ws + 67637248);    // 33.5 MB
    unsigned short* h1T = (unsigned short*)(ws + 101191680);   // 33.5 MB

    detect_kernel<<<1, 256, 0, stream>>>(idx, flag);
    rowsum_kernel<<<B_SZ * N_SZ / 4, 256, 0, stream>>>(A, A2, d);
    mix_kernel<<<B_SZ * N_SZ / 8, 256, 0, stream>>>(A2, d);
    gather_kernel<<<dim3(4, B_SZ), 256, 0, stream>>>(idx, emb, flag, h0T);
    gemm_kernel<<<dim3(4, B_SZ), 256, 0, stream>>>(A2, h0T, h1T, nullptr, 0);
    gemm_kernel<<<dim3(4, B_SZ), 256, 0, stream>>>(A2, h1T, nullptr, out, 1);
}